// Round 12
// baseline (162.372 us; speedup 1.0000x reference)
//
#include <hip/hip_runtime.h>
#include <math.h>

// Problem constants
#define B_ 32
#define D_ 512
#define N_ 1024
#define T_ 32768
#define SCALE 0.04419417382415922f  // 512^-0.5

typedef unsigned short u16;
typedef __attribute__((ext_vector_type(8))) short bf16x8;
typedef __attribute__((ext_vector_type(4))) float f32x4;
typedef __attribute__((ext_vector_type(8))) unsigned short u16x8;

__device__ __forceinline__ u16 bf16_rn(float f) {
    unsigned u = __float_as_uint(f);
    u += 0x7FFFu + ((u >> 16) & 1u);
    return (u16)(u >> 16);
}
__device__ __forceinline__ float bf16f(u16 h) {
    return __uint_as_float(((unsigned)h) << 16);
}

// async global->LDS, 16B/lane; LDS dest = wave-uniform base (+lane*16 by HW)
__device__ __forceinline__ void g2l16(const u16* g, u16* lds) {
    __builtin_amdgcn_global_load_lds(
        (const __attribute__((address_space(1))) unsigned int*)g,
        (__attribute__((address_space(3))) unsigned int*)lds, 16, 0, 0);
}

__device__ __forceinline__ float waveRedSum(float v) {
#pragma unroll
    for (int off = 32; off > 0; off >>= 1) v += __shfl_xor(v, off, 64);
    return v;
}

// ---------------- conversion kernels ----------------

// Wq/Wk/Wf [512][512] fp32 -> bf16
__global__ __launch_bounds__(256) void convw_k(const float* __restrict__ W0,
                                               const float* __restrict__ W1,
                                               const float* __restrict__ W2,
                                               u16* O0, u16* O1, u16* O2) {
    const int s = blockIdx.y;
    const float* src = (s == 0) ? W0 : ((s == 1) ? W1 : W2);
    u16* O = (s == 0) ? O0 : ((s == 1) ? O1 : O2);
    const size_t i0 = (size_t)blockIdx.x * 2048 + threadIdx.x * 8;
    u16 o[8];
#pragma unroll
    for (int j = 0; j < 8; ++j) o[j] = bf16_rn(src[i0 + j]);
    *(u16x8*)&O[i0] = *(const u16x8*)&o[0];
}

// ---------------- small math kernels ----------------

// finalize per-row norms: ssqQ/ssqK -> rscale (in place), qwr -> gctx coeff
__global__ __launch_bounds__(256) void finalize_k(float* __restrict__ ssqQ,
                                                  float* __restrict__ ssqK,
                                                  float* __restrict__ qwr,
                                                  float* __restrict__ Sb) {
    __shared__ float red[4];
    const int i = blockIdx.x * 256 + threadIdx.x;
    const float rq = 1.f / fmaxf(sqrtf(ssqQ[i]), 1e-12f);
    ssqQ[i] = rq;
    const float rk = 1.f / fmaxf(sqrtf(ssqK[i]), 1e-12f);
    ssqK[i] = rk;
    const float qwp = qwr[i] * rq;   // normalized-q dot wg
    qwr[i] = qwp * rq;               // coefficient for gctx (extra rsQ for q-hat)
    float s = qwp * qwp;
    s = waveRedSum(s);
    if ((threadIdx.x & 63) == 0) red[threadIdx.x >> 6] = s;
    __syncthreads();
    if (threadIdx.x == 0)
        atomicAdd(Sb + (blockIdx.x >> 2), red[0] + red[1] + red[2] + red[3]);
}

// graw[b,d] = sum_n coeff[b,n] * Qraw[b,n,d]
__global__ __launch_bounds__(512) void gctx_k(const float* __restrict__ qw,
                                              const u16* __restrict__ Qn,
                                              float* __restrict__ g) {
    const int b = blockIdx.y;
    const int n0 = blockIdx.x * 128;
    const int d = threadIdx.x;
    const u16* qp = Qn + ((size_t)b * N_ + n0) * D_ + d;
    const float* wp = qw + (size_t)b * N_ + n0;
    float acc = 0.f;
    for (int n = 0; n < 128; ++n) acc += wp[n] * bf16f(qp[(size_t)n * D_]);
    atomicAdd(g + b * D_ + d, acc);
}

// WpG[b][e][c] = bf16( Wp[e][c] * graw[b][c] * f_b ),  f_b from Sb
__global__ __launch_bounds__(256) void scalewp_k(const float* __restrict__ Wp,
                                                 const float* __restrict__ g,
                                                 const float* __restrict__ Sb,
                                                 u16* __restrict__ WpG) {
    const int b = blockIdx.y;
    const float fb = SCALE / fmaxf(SCALE * sqrtf(Sb[b]), 1e-12f);
    const size_t f0 = (size_t)blockIdx.x * 2048 + threadIdx.x * 8;
    const int c = (int)(f0 & 511);
    u16 o[8];
#pragma unroll
    for (int j = 0; j < 8; ++j)
        o[j] = bf16_rn(Wp[f0 + j] * g[b * D_ + c + j] * fb);
    *(u16x8*)&WpG[(size_t)b * 262144 + f0] = *(const u16x8*)&o[0];
}

// ---------------- unified 2-phase double-buffered MFMA GEMM ----------------
// 128x128 tile, BK=64, 8 waves (4Mx2N of 32x64), 512 thr, 16x16x32 bf16.
// Schedule (T3-minimum): stage tile s+1 into buf^1 BEFORE computing tile s;
// one __syncthreads per K-step (compiler's pre-barrier vmcnt(0)/lgkmcnt(0)
// drains loads whose latency overlapped the MFMA phase).
// MODE 0: A = x fp32 [B][C][N] read directly (scalar loads 2 tiles ahead,
//         pack->ds_write into next buf); B = Wq/Wk bf16; stores RAW Q/K bf16
//         + atomicAdd row sumsq + raw.wg dots. Grid 2048, XCD-pinned rows.
// MODE 1: A=Kraw, B=WpG[batch] (batch->XCD); out bf16 in place over Qraw:
//         val = acc*rsK[m] + bp[n] + qraw*rsQ[m]. Grid 1024.
// MODE 2: A=Wf rows(e), B=Y rows(t); fp32 transposed store out[b][e][n].
//         Grid 1024, token-tile->XCD.
template <int MODE>
__global__ __launch_bounds__(512, 4) void mg(
        const float* __restrict__ x, const u16* __restrict__ Ag,
        const u16* __restrict__ B0, const u16* __restrict__ B1,
        const float* __restrict__ bias0, const float* __restrict__ bias1,
        const float* __restrict__ wg,
        float* __restrict__ ssqQ, float* __restrict__ ssqK,
        float* __restrict__ qwr,
        const float* __restrict__ rsA, const float* __restrict__ rsQ,
        u16* uout0, u16* uout1, float* __restrict__ fout) {
    __shared__ u16 As[2][128 * 64];
    __shared__ u16 Bs[2][128 * 64];
    const int tid = threadIdx.x;
    const int l = tid & 63, w = tid >> 6;
    const int gid = blockIdx.x, xcd = gid & 7;

    int t0, e0, batch;
    bool sel = false;
    if (MODE == 0) {
        const int bx = (gid >> 3) & 7;       // 8 col variants share A panel
        const int by = (gid >> 6) * 8 + xcd; // row tile -> fixed XCD
        t0 = by * 128; sel = bx >= 4; e0 = (bx & 3) * 128; batch = by >> 3;
    } else if (MODE == 1) {
        const int j = gid >> 3;
        batch = (j >> 5) * 8 + xcd;          // batch -> fixed XCD
        const int r = j & 31;
        t0 = (batch * 8 + (r >> 2)) * 128;
        e0 = (r & 3) * 128;
    } else {
        e0 = ((gid >> 3) & 3) * 128;
        const int rowt = (gid >> 5) * 8 + xcd;  // token tile -> fixed XCD
        t0 = rowt * 128; batch = rowt >> 3;
    }
    const u16* B = (MODE == 0) ? (sel ? B1 : B0)
                 : (MODE == 1) ? B0 + (size_t)batch * 262144 : B0;
    const float* bias = (MODE == 0) ? (sel ? bias1 : bias0) : bias0;
    u16* uout = (MODE == 0) ? (sel ? uout1 : uout0) : uout0;
    const int arow0 = (MODE == 2) ? e0 : t0;
    const int brow0 = (MODE == 2) ? t0 : e0;

    // staging addresses: 2 g2l16/wave each for A (modes 1/2) and B (all)
    size_t gA[2], gB[2];
    int lAB[2];
#pragma unroll
    for (int i = 0; i < 2; ++i) {
        const int rr = w * 16 + i * 8 + (l >> 3);
        const int sw = ((l & 7) ^ (rr & 7)) * 8;
        gA[i] = (size_t)(arow0 + rr) * 512 + sw;
        gB[i] = (size_t)(brow0 + rr) * 512 + sw;
        lAB[i] = (w * 16 + i * 8) * 64;
    }
    // A mode 0: direct x; thread -> token tr, chunks ch0, ch0+1
    const int tr = tid & 127;
    const int ch0 = (tid >> 7) * 2;
    const float* xrow = nullptr;
    int wA0 = 0, wA1 = 0;
    if (MODE == 0) {
        xrow = x + (((size_t)(batch * D_ + ch0 * 8)) << 10) + (t0 & 1023) + tr;
        wA0 = tr * 64 + ((ch0 ^ (tr & 7)) * 8);
        wA1 = tr * 64 + (((ch0 + 1) ^ (tr & 7)) * 8);
    }

    // fragment read offsets (XOR involution), wave grid 4(M) x 2(N)
    const int wr = w >> 1, wc = w & 1, kg = l >> 4, r16 = l & 15;
    int aoff[2][2], boff[4][2];
#pragma unroll
    for (int f = 0; f < 2; ++f)
#pragma unroll
        for (int h = 0; h < 2; ++h) {
            const int ra = wr * 32 + f * 16 + r16;
            aoff[f][h] = ra * 64 + (((h * 4 + kg) ^ (ra & 7)) * 8);
        }
#pragma unroll
    for (int f = 0; f < 4; ++f)
#pragma unroll
        for (int h = 0; h < 2; ++h) {
            const int rb = wc * 64 + f * 16 + r16;
            boff[f][h] = rb * 64 + (((h * 4 + kg) ^ (rb & 7)) * 8);
        }

    f32x4 acc[2][4];
#pragma unroll
    for (int i = 0; i < 2; ++i)
#pragma unroll
        for (int j = 0; j < 4; ++j) acc[i][j] = 0.f;

    // ---- prologue: stage tile 0 into buf 0; mode0 prefetch tile 1 regs
    float ar[16];
    if (MODE == 0) {
#pragma unroll
        for (int j = 0; j < 16; ++j) ar[j] = xrow[(size_t)j << 10];
    }
#pragma unroll
    for (int i = 0; i < 2; ++i) g2l16(B + gB[i], &Bs[0][lAB[i]]);
    if (MODE != 0) {
#pragma unroll
        for (int i = 0; i < 2; ++i) g2l16(Ag + gA[i], &As[0][lAB[i]]);
    } else {
        u16 pk[16];
#pragma unroll
        for (int j = 0; j < 16; ++j) pk[j] = bf16_rn(ar[j]);
        *(u16x8*)&As[0][wA0] = *(const u16x8*)&pk[0];
        *(u16x8*)&As[0][wA1] = *(const u16x8*)&pk[8];
#pragma unroll
        for (int j = 0; j < 16; ++j) ar[j] = xrow[(size_t)(64 + j) << 10];
    }
    __syncthreads();

    // ---- 2-phase main loop: one barrier per K-step
    int cur = 0;
#pragma unroll 1
    for (int s = 0; s < 8; ++s) {
        const int nxt = cur ^ 1;
        if (s < 7) {                       // issue next-tile loads FIRST
            const int cn = (s + 1) * 64;
#pragma unroll
            for (int i = 0; i < 2; ++i) g2l16(B + gB[i] + cn, &Bs[nxt][lAB[i]]);
            if (MODE != 0) {
#pragma unroll
                for (int i = 0; i < 2; ++i)
                    g2l16(Ag + gA[i] + cn, &As[nxt][lAB[i]]);
            }
        }
        // compute current tile
#pragma unroll
        for (int h = 0; h < 2; ++h) {
            bf16x8 av[2], bv[4];
#pragma unroll
            for (int f = 0; f < 2; ++f)
                av[f] = *(const bf16x8*)&As[cur][aoff[f][h]];
#pragma unroll
            for (int f = 0; f < 4; ++f)
                bv[f] = *(const bf16x8*)&Bs[cur][boff[f][h]];
#pragma unroll
            for (int i = 0; i < 2; ++i)
#pragma unroll
                for (int j = 0; j < 4; ++j)
                    acc[i][j] = __builtin_amdgcn_mfma_f32_16x16x32_bf16(
                        av[i], bv[j], acc[i][j], 0, 0, 0);
        }
        if (MODE == 0 && s < 7) {
            // write next A tile (regs loaded 1 step ago); prefetch s+2
            u16 pk[16];
#pragma unroll
            for (int j = 0; j < 16; ++j) pk[j] = bf16_rn(ar[j]);
            *(u16x8*)&As[nxt][wA0] = *(const u16x8*)&pk[0];
            *(u16x8*)&As[nxt][wA1] = *(const u16x8*)&pk[8];
            if (s < 6) {
#pragma unroll
                for (int j = 0; j < 16; ++j)
                    ar[j] = xrow[(size_t)((s + 2) * 64 + j) << 10];
            }
        }
        __syncthreads();
        cur = nxt;
    }

    // ---- epilogues (C/D: col = lane&15, row = (lane>>4)*4 + reg)
    const int mb = wr * 32 + kg * 4;
    const int nb = wc * 64 + r16;
    if (MODE == 0) {
        float bb[4], wgv[4];
#pragma unroll
        for (int fn = 0; fn < 4; ++fn) {
            const int n = e0 + nb + fn * 16;
            bb[fn] = bias[n];
            wgv[fn] = sel ? 0.f : wg[n];
        }
        float* ssq = sel ? ssqK : ssqQ;
#pragma unroll
        for (int fm = 0; fm < 2; ++fm) {
#pragma unroll
            for (int q = 0; q < 4; ++q) {
                const int m = t0 + mb + fm * 16 + q;
                float s2 = 0.f, wd = 0.f;
#pragma unroll
                for (int fn = 0; fn < 4; ++fn) {
                    const float val = acc[fm][fn][q] + bb[fn];
                    uout[(size_t)m * 512 + e0 + nb + fn * 16] = bf16_rn(val);
                    s2 += val * val;
                    wd += val * wgv[fn];
                }
#pragma unroll
                for (int off = 1; off < 16; off <<= 1) {
                    s2 += __shfl_xor(s2, off, 64);
                    wd += __shfl_xor(wd, off, 64);
                }
                if (r16 == 0) {
                    atomicAdd(ssq + m, s2);
                    if (!sel) atomicAdd(qwr + m, wd);
                }
            }
        }
    } else if (MODE == 1) {
#pragma unroll
        for (int fm = 0; fm < 2; ++fm) {
            const int m0 = t0 + mb + fm * 16;
            const float4 ra4 = *(const float4*)(rsA + m0);
            const float4 rq4 = *(const float4*)(rsQ + m0);
            const float ra_[4] = {ra4.x, ra4.y, ra4.z, ra4.w};
            const float rq_[4] = {rq4.x, rq4.y, rq4.z, rq4.w};
#pragma unroll
            for (int fn = 0; fn < 4; ++fn) {
                const int n = e0 + nb + fn * 16;
                const float bb = bias[n];
#pragma unroll
                for (int q = 0; q < 4; ++q) {
                    const size_t idx = (size_t)(m0 + q) * 512 + n;
                    const float val = acc[fm][fn][q] * ra_[q] + bb +
                                      bf16f(uout[idx]) * rq_[q];
                    uout[idx] = bf16_rn(val);
                }
            }
        }
    } else {
#pragma unroll
        for (int fm = 0; fm < 2; ++fm)
#pragma unroll
            for (int fn = 0; fn < 4; ++fn) {
                const int ntok = (t0 & 1023) + nb + fn * 16;
#pragma unroll
                for (int q = 0; q < 4; ++q) {
                    const int e = e0 + mb + fm * 16 + q;
                    fout[((size_t)(batch * D_ + e) << 10) + ntok] =
                        acc[fm][fn][q] + bias[e];
                }
            }
    }
}

// ---------------- launcher ----------------

extern "C" void kernel_launch(void* const* d_in, const int* in_sizes, int n_in,
                              void* d_out, int out_size, void* d_ws, size_t ws_size,
                              hipStream_t stream) {
    const float* x  = (const float*)d_in[0];
    const float* Wq = (const float*)d_in[1];
    const float* bq = (const float*)d_in[2];
    const float* Wk = (const float*)d_in[3];
    const float* bk = (const float*)d_in[4];
    const float* wg = (const float*)d_in[5];
    const float* Wp = (const float*)d_in[6];
    const float* bp = (const float*)d_in[7];
    const float* Wf = (const float*)d_in[8];
    const float* bf = (const float*)d_in[9];
    float* out = (float*)d_out;

    // ws map (bytes), peak ~98 MB:
    // [0,16M)   WpG
    // [32M,64M) Qraw bf16 -> Y (mg<1> in place)
    // [64M,96M) Kraw bf16
    // [96M,..)  Wqbf, Wkbf, Wfbf, then zeroed stats region:
    //           ssqQ[T] ssqK[T] qwr[T] G[B*D] Sb[B]
    char* Wb = (char*)d_ws;
    u16* WpG = (u16*)Wb;
    u16* Qn  = (u16*)(Wb + 33554432ull);
    u16* Kn  = (u16*)(Wb + 67108864ull);
    char* S  = Wb + 100663296ull;
    u16* Wqbf = (u16*)S;
    u16* Wkbf = (u16*)(S + 524288ull);
    u16* Wfbf = (u16*)(S + 1048576ull);
    char* Z   = S + 1572864ull;
    float* SSQQ = (float*)Z;
    float* SSQK = (float*)(Z + 131072ull);
    float* QWR  = (float*)(Z + 262144ull);
    float* G    = (float*)(Z + 393216ull);
    float* Sb   = (float*)(Z + 458752ull);
    const size_t ZBYTES = 458752ull + 128ull;

    const dim3 blk(256);

    // 1. weights -> bf16
    convw_k<<<dim3(128, 3), blk, 0, stream>>>(Wq, Wk, Wf, Wqbf, Wkbf, Wfbf);
    // 2. zero the stats region (atomic accumulators)
    hipMemsetAsync(Z, 0, ZBYTES, stream);
    // 3. fused q/k projection (direct x read) + row-norm stats
    mg<0><<<dim3(2048), dim3(512), 0, stream>>>(x, nullptr, Wqbf, Wkbf, bq, bk,
                                                wg, SSQQ, SSQK, QWR, nullptr,
                                                nullptr, Qn, Kn, nullptr);
    // 4. finalize rscales, gctx coeff, Sb
    finalize_k<<<dim3(128), blk, 0, stream>>>(SSQQ, SSQK, QWR, Sb);
    // 5. graw = sum_n coeff_n * qraw_n
    gctx_k<<<dim3(8, B_), dim3(512), 0, stream>>>(QWR, Qn, G);
    // 6. WpG[b] = Wp * graw[b] * f_b
    scalewp_k<<<dim3(128, B_), blk, 0, stream>>>(Wp, G, Sb, WpG);
    // 7. Y = k_hat @ WpG[b]^T + bp + q_hat  (bf16, in place over Qn)
    mg<1><<<dim3(1024), dim3(512), 0, stream>>>(nullptr, Kn, WpG, nullptr, bp,
                                                nullptr, nullptr, nullptr,
                                                nullptr, nullptr, SSQK, SSQQ,
                                                Qn, nullptr, nullptr);
    // 8. out[b][e][n] = Wf x Y^T + bf  (fp32, final layout)
    mg<2><<<dim3(1024), dim3(512), 0, stream>>>(nullptr, Wfbf, Qn, nullptr, bf,
                                                nullptr, nullptr, nullptr,
                                                nullptr, nullptr, nullptr,
                                                nullptr, Qn, nullptr, out);
}

// Round 13
// 148.173 us; speedup vs baseline: 1.0958x; 1.0958x over previous
//
#include <hip/hip_runtime.h>
#include <hip/hip_bf16.h>
#include <math.h>

// Problem constants
#define B_ 32
#define D_ 512
#define N_ 1024
#define T_ 32768
#define SCALE 0.04419417382415922f  // 512^-0.5

typedef unsigned short u16;
typedef __attribute__((ext_vector_type(8))) short bf16x8;
typedef __attribute__((ext_vector_type(4))) float f32x4;
typedef __attribute__((ext_vector_type(8))) unsigned short u16x8;
typedef __attribute__((ext_vector_type(4))) unsigned int u32x4;

__device__ __forceinline__ u16 bf16_rn(float f) {
    unsigned u = __float_as_uint(f);
    u += 0x7FFFu + ((u >> 16) & 1u);
    return (u16)(u >> 16);
}
__device__ __forceinline__ float bf16f(u16 h) {
    return __uint_as_float(((unsigned)h) << 16);
}
// pack 2 floats -> 2 bf16 (RNE) in one u32 (low = a, high = b)
__device__ __forceinline__ unsigned pkbf(float a, float b) {
    __hip_bfloat162 h = __float22bfloat162_rn(make_float2(a, b));
    return *reinterpret_cast<unsigned*>(&h);
}

// async global->LDS, 16B/lane; LDS dest = wave-uniform base (+lane*16 by HW)
__device__ __forceinline__ void g2l16(const u16* g, u16* lds) {
    __builtin_amdgcn_global_load_lds(
        (const __attribute__((address_space(1))) unsigned int*)g,
        (__attribute__((address_space(3))) unsigned int*)lds, 16, 0, 0);
}

__device__ __forceinline__ float waveRedSum(float v) {
#pragma unroll
    for (int off = 32; off > 0; off >>= 1) v += __shfl_xor(v, off, 64);
    return v;
}

// ---------------- conversion kernels ----------------

// Wq/Wk/Wf [512][512] fp32 -> bf16
__global__ __launch_bounds__(256) void convw_k(const float* __restrict__ W0,
                                               const float* __restrict__ W1,
                                               const float* __restrict__ W2,
                                               u16* O0, u16* O1, u16* O2) {
    const int s = blockIdx.y;
    const float* src = (s == 0) ? W0 : ((s == 1) ? W1 : W2);
    u16* O = (s == 0) ? O0 : ((s == 1) ? O1 : O2);
    const size_t i0 = (size_t)blockIdx.x * 2048 + threadIdx.x * 8;
    u16 o[8];
#pragma unroll
    for (int j = 0; j < 8; ++j) o[j] = bf16_rn(src[i0 + j]);
    *(u16x8*)&O[i0] = *(const u16x8*)&o[0];
}

// ---------------- small math kernels ----------------

// finalize per-row norms: ssqQ/ssqK -> rscale (in place), qwr -> gctx coeff
__global__ __launch_bounds__(256) void finalize_k(float* __restrict__ ssqQ,
                                                  float* __restrict__ ssqK,
                                                  float* __restrict__ qwr,
                                                  float* __restrict__ Sb) {
    __shared__ float red[4];
    const int i = blockIdx.x * 256 + threadIdx.x;
    const float rq = 1.f / fmaxf(sqrtf(ssqQ[i]), 1e-12f);
    ssqQ[i] = rq;
    const float rk = 1.f / fmaxf(sqrtf(ssqK[i]), 1e-12f);
    ssqK[i] = rk;
    const float qwp = qwr[i] * rq;   // normalized-q dot wg
    qwr[i] = qwp * rq;               // coefficient for gctx (extra rsQ for q-hat)
    float s = qwp * qwp;
    s = waveRedSum(s);
    if ((threadIdx.x & 63) == 0) red[threadIdx.x >> 6] = s;
    __syncthreads();
    if (threadIdx.x == 0)
        atomicAdd(Sb + (blockIdx.x >> 2), red[0] + red[1] + red[2] + red[3]);
}

// graw[b,d] = sum_n coeff[b,n] * Qraw[b,n,d]
__global__ __launch_bounds__(512) void gctx_k(const float* __restrict__ qw,
                                              const u16* __restrict__ Qn,
                                              float* __restrict__ g) {
    const int b = blockIdx.y;
    const int n0 = blockIdx.x * 128;
    const int d = threadIdx.x;
    const u16* qp = Qn + ((size_t)b * N_ + n0) * D_ + d;
    const float* wp = qw + (size_t)b * N_ + n0;
    float acc = 0.f;
    for (int n = 0; n < 128; ++n) acc += wp[n] * bf16f(qp[(size_t)n * D_]);
    atomicAdd(g + b * D_ + d, acc);
}

// WpG[b][e][c] = bf16( Wp[e][c] * graw[b][c] * f_b ),  f_b from Sb
__global__ __launch_bounds__(256) void scalewp_k(const float* __restrict__ Wp,
                                                 const float* __restrict__ g,
                                                 const float* __restrict__ Sb,
                                                 u16* __restrict__ WpG) {
    const int b = blockIdx.y;
    const float fb = SCALE / fmaxf(SCALE * sqrtf(Sb[b]), 1e-12f);
    const size_t f0 = (size_t)blockIdx.x * 2048 + threadIdx.x * 8;
    const int c = (int)(f0 & 511);
    u16 o[8];
#pragma unroll
    for (int j = 0; j < 8; ++j)
        o[j] = bf16_rn(Wp[f0 + j] * g[b * D_ + c + j] * fb);
    *(u16x8*)&WpG[(size_t)b * 262144 + f0] = *(const u16x8*)&o[0];
}

// ---------------- GEMM 0: q/k projection, fused norm-stats ----------------
// Tile 128(M)x256(N), BK=64, 8 waves (2x4), 16x16x32 bf16 MFMA, XCD-swizzled.
// A read DIRECTLY from x fp32 [B][C][N]: wave w owns c-chunk w; lane l owns
// tokens 2l,2l+1 via 8x float2 (coalesced). Pack via v_cvt_pk (RNE), 2x
// ds_write_b128 with chunk-XOR swizzle. A(s+1) loads are issued INSIDE the
// MFMA phase (after barrier2) so their latency overlaps compute instead of
// being drained by the barrier (T14 issue-early).
// B (weights bf16) via global_load_lds + XOR-swizzled source.
// Stores RAW (biased) Q/K bf16 + atomicAdd per-row sumsq and raw.wg dots.
__global__ __launch_bounds__(512, 4) void mgemm0(
        const float* __restrict__ x, const u16* __restrict__ B0,
        const u16* __restrict__ B1,
        const float* __restrict__ bias0, const float* __restrict__ bias1,
        const float* __restrict__ wg,
        float* __restrict__ ssqQ, float* __restrict__ ssqK,
        float* __restrict__ qwr, u16* uout0, u16* uout1) {
    __shared__ u16 As[128 * 64];
    __shared__ u16 Bs[256 * 64];
    const int tid = threadIdx.x;
    const int l = tid & 63, w = tid >> 6;
    const int gid = blockIdx.x;
    const int xcd = gid & 7;
    const int bx = (gid >> 3) & 3;           // col tile (shares A panel)
    const int by = (gid >> 5) * 8 + xcd;     // row tile -> fixed XCD
    const int t0 = by * 128;
    const bool sel = bx >= 2;                // false: Q, true: K
    const int e0 = (bx & 1) * 256;
    const u16* B = sel ? B1 : B0;
    const float* bias = sel ? bias1 : bias0;
    u16* uout = sel ? uout1 : uout0;
    float* ssq = sel ? ssqK : ssqQ;
    const int batch0 = t0 >> 10;

    // ---- A staging: wave w -> c-chunk w (8 c); lane l -> tokens 2l, 2l+1
    const float* xbase = x + (((size_t)(batch0 * D_ + w * 8)) << 10) +
                         (t0 & 1023) + 2 * l;
    const int r0 = 2 * l, r1 = 2 * l + 1;
    u16* wA0 = &As[r0 * 64 + ((w ^ (r0 & 7)) * 8)];
    u16* wA1 = &As[r1 * 64 + ((w ^ (r1 & 7)) * 8)];
    // ---- B staging (g2l16, linear LDS + XOR-swizzled source)
    size_t gB[4];
    u16* ldsB[4];
#pragma unroll
    for (int i = 0; i < 4; ++i) {
        const int rr = w * 32 + i * 8 + (l >> 3);
        gB[i] = (size_t)(e0 + rr) * 512 + (((l & 7) ^ (rr & 7)) * 8);
        ldsB[i] = Bs + (w * 32 + i * 8) * 64;
    }

    // fragment read offsets (XOR involution on both A and B)
    const int wr = w >> 2, wc = w & 3, kg = l >> 4, r16 = l & 15;
    int aoff[4][2], boff[4][2];
#pragma unroll
    for (int f = 0; f < 4; ++f)
#pragma unroll
        for (int h = 0; h < 2; ++h) {
            const int ra = wr * 64 + f * 16 + r16;
            aoff[f][h] = ra * 64 + (((h * 4 + kg) ^ (ra & 7)) * 8);
            const int rb = wc * 64 + f * 16 + r16;
            boff[f][h] = rb * 64 + (((h * 4 + kg) ^ (rb & 7)) * 8);
        }

    f32x4 acc[4][4];
#pragma unroll
    for (int i = 0; i < 4; ++i)
#pragma unroll
        for (int j = 0; j < 4; ++j) acc[i][j] = 0.f;

    // prologue: fetch A regs for s=0
    float2 va[8];
#pragma unroll
    for (int j = 0; j < 8; ++j)
        va[j] = *(const float2*)(xbase + ((size_t)j << 10));

#pragma unroll 1
    for (int s = 0; s < 8; ++s) {
        const int c0 = s * 64;
        __syncthreads();             // prior tile consumed; A(s) regs arrived
        // pack + write A(s): 8 cvt_pk + 2 ds_write_b128
        {
            u32x4 p0, p1;
#pragma unroll
            for (int jj = 0; jj < 4; ++jj) {
                p0[jj] = pkbf(va[2 * jj].x, va[2 * jj + 1].x);
                p1[jj] = pkbf(va[2 * jj].y, va[2 * jj + 1].y);
            }
            *(u32x4*)wA0 = p0;
            *(u32x4*)wA1 = p1;
        }
        // B tile via async load
#pragma unroll
        for (int i = 0; i < 4; ++i) g2l16(B + gB[i] + c0, ldsB[i]);
        __syncthreads();             // drain -> LDS ready
        // issue A(s+1) loads NOW: latency overlaps the MFMA phase below
        if (s < 7) {
#pragma unroll
            for (int j = 0; j < 8; ++j)
                va[j] = *(const float2*)(xbase + ((size_t)(c0 + 64 + j) << 10));
        }
#pragma unroll
        for (int h = 0; h < 2; ++h) {
            bf16x8 av[4], bv[4];
#pragma unroll
            for (int f = 0; f < 4; ++f) {
                av[f] = *(const bf16x8*)&As[aoff[f][h]];
                bv[f] = *(const bf16x8*)&Bs[boff[f][h]];
            }
#pragma unroll
            for (int i = 0; i < 4; ++i)
#pragma unroll
                for (int j = 0; j < 4; ++j)
                    acc[i][j] = __builtin_amdgcn_mfma_f32_16x16x32_bf16(
                        av[i], bv[j], acc[i][j], 0, 0, 0);
        }
    }

    // epilogue: raw store + row sumsq / wg-dot partials
    const int mb = wr * 64 + kg * 4;
    const int nb = wc * 64 + r16;
    float bb[4], wgv[4];
#pragma unroll
    for (int fn = 0; fn < 4; ++fn) {
        const int n = e0 + nb + fn * 16;
        bb[fn] = bias[n];
        wgv[fn] = sel ? 0.f : wg[n];
    }
#pragma unroll
    for (int fm = 0; fm < 4; ++fm) {
#pragma unroll
        for (int q = 0; q < 4; ++q) {
            const int m = t0 + mb + fm * 16 + q;
            float s2 = 0.f, wd = 0.f;
#pragma unroll
            for (int fn = 0; fn < 4; ++fn) {
                const float val = acc[fm][fn][q] + bb[fn];
                uout[(size_t)m * 512 + e0 + nb + fn * 16] = bf16_rn(val);
                s2 += val * val;
                wd += val * wgv[fn];
            }
#pragma unroll
            for (int off = 1; off < 16; off <<= 1) {
                s2 += __shfl_xor(s2, off, 64);
                wd += __shfl_xor(wd, off, 64);
            }
            if (r16 == 0) {
                atomicAdd(ssq + m, s2);
                if (!sel) atomicAdd(qwr + m, wd);
            }
        }
    }
}

// ---------------- GEMM 1/2: 128x128, 4 waves, XCD-swizzled ----------------
// MODE 1: A=Kraw; B=WpG[batch]; out bf16 in place over Qraw:
//         val = acc*rsK[m] + bp[n] + qraw*rsQ[m]
//         decode pins BATCH -> XCD so WpG[b] is fetched by one L2 only.
// MODE 2: A=Wf rows(e); B=Y rows(t); fp32 transposed store out[b][e][n];
//         decode pins token-tile -> XCD (B-panel reuse).
template <int MODE>
__global__ __launch_bounds__(256) void mgemm12(
        const u16* __restrict__ A, const u16* __restrict__ B0,
        const float* __restrict__ bias,
        const float* __restrict__ rsA, const float* __restrict__ rsQ,
        u16* uout, float* __restrict__ fout) {
    __shared__ u16 As[128 * 64];
    __shared__ u16 Bs[128 * 64];
    const int tid = threadIdx.x;
    const int l = tid & 63, w = tid >> 6;
    const int gid = blockIdx.x;
    const int xcd = gid & 7;

    int rowt, col, batch;
    if (MODE == 1) {
        const int j = gid >> 3;
        batch = (j >> 5) * 8 + xcd;          // batch -> fixed XCD
        const int r = j & 31;
        rowt = batch * 8 + (r >> 2);
        col = r & 3;
    } else {
        col = (gid >> 3) & 3;                // e tile
        rowt = (gid >> 5) * 8 + xcd;         // token tile -> fixed XCD
        batch = rowt >> 3;
    }
    const int tt0 = rowt * 128;              // token base
    const int e0 = col * 128;
    const u16* B = (MODE == 1) ? B0 + (size_t)batch * 262144 : B0;
    const int arow0 = (MODE == 2) ? e0 : tt0;
    const int brow0 = (MODE == 2) ? tt0 : e0;

    size_t gA[4], gB[4];
    u16 *ldsA[4], *ldsB[4];
#pragma unroll
    for (int i = 0; i < 4; ++i) {
        const int rr = w * 32 + i * 8 + (l >> 3);
        const int sw = ((l & 7) ^ (rr & 7)) * 8;
        gA[i] = (size_t)(arow0 + rr) * 512 + sw;
        gB[i] = (size_t)(brow0 + rr) * 512 + sw;
        ldsA[i] = As + (w * 32 + i * 8) * 64;
        ldsB[i] = Bs + (w * 32 + i * 8) * 64;
    }

    const int wr = w >> 1, wc = w & 1, kg = l >> 4, r16 = l & 15;
    int aoff[4][2], boff[4][2];
#pragma unroll
    for (int f = 0; f < 4; ++f)
#pragma unroll
        for (int h = 0; h < 2; ++h) {
            const int ra = wr * 64 + f * 16 + r16;
            aoff[f][h] = ra * 64 + (((h * 4 + kg) ^ (ra & 7)) * 8);
            const int rb = wc * 64 + f * 16 + r16;
            boff[f][h] = rb * 64 + (((h * 4 + kg) ^ (rb & 7)) * 8);
        }

    f32x4 acc[4][4];
#pragma unroll
    for (int i = 0; i < 4; ++i)
#pragma unroll
        for (int j = 0; j < 4; ++j) acc[i][j] = 0.f;

#pragma unroll 1
    for (int c0 = 0; c0 < 512; c0 += 64) {
        __syncthreads();
#pragma unroll
        for (int i = 0; i < 4; ++i) {
            g2l16(A + gA[i] + c0, ldsA[i]);
            g2l16(B + gB[i] + c0, ldsB[i]);
        }
        __syncthreads();
#pragma unroll
        for (int h = 0; h < 2; ++h) {
            bf16x8 av[4], bv[4];
#pragma unroll
            for (int f = 0; f < 4; ++f) {
                av[f] = *(const bf16x8*)&As[aoff[f][h]];
                bv[f] = *(const bf16x8*)&Bs[boff[f][h]];
            }
#pragma unroll
            for (int i = 0; i < 4; ++i)
#pragma unroll
                for (int j = 0; j < 4; ++j)
                    acc[i][j] = __builtin_amdgcn_mfma_f32_16x16x32_bf16(
                        av[i], bv[j], acc[i][j], 0, 0, 0);
        }
    }

    const int mb = wr * 64 + kg * 4;
    const int nb = wc * 64 + r16;
    if (MODE == 1) {
#pragma unroll
        for (int fm = 0; fm < 4; ++fm) {
            const int m0 = tt0 + mb + fm * 16;
            const float4 ra4 = *(const float4*)(rsA + m0);
            const float4 rq4 = *(const float4*)(rsQ + m0);
            const float ra_[4] = {ra4.x, ra4.y, ra4.z, ra4.w};
            const float rq_[4] = {rq4.x, rq4.y, rq4.z, rq4.w};
#pragma unroll
            for (int fn = 0; fn < 4; ++fn) {
                const int n = e0 + nb + fn * 16;
                const float bb = bias[n];
#pragma unroll
                for (int q = 0; q < 4; ++q) {
                    const size_t idx = (size_t)(m0 + q) * 512 + n;
                    const float val = acc[fm][fn][q] * ra_[q] + bb +
                                      bf16f(uout[idx]) * rq_[q];
                    uout[idx] = bf16_rn(val);
                }
            }
        }
    } else {
#pragma unroll
        for (int fm = 0; fm < 4; ++fm)
#pragma unroll
            for (int fn = 0; fn < 4; ++fn) {
                const int ntok = (tt0 & 1023) + nb + fn * 16;
#pragma unroll
                for (int q = 0; q < 4; ++q) {
                    const int e = e0 + mb + fm * 16 + q;
                    fout[((size_t)(batch * D_ + e) << 10) + ntok] =
                        acc[fm][fn][q] + bias[e];
                }
            }
    }
}

// ---------------- launcher ----------------

extern "C" void kernel_launch(void* const* d_in, const int* in_sizes, int n_in,
                              void* d_out, int out_size, void* d_ws, size_t ws_size,
                              hipStream_t stream) {
    const float* x  = (const float*)d_in[0];
    const float* Wq = (const float*)d_in[1];
    const float* bq = (const float*)d_in[2];
    const float* Wk = (const float*)d_in[3];
    const float* bk = (const float*)d_in[4];
    const float* wg = (const float*)d_in[5];
    const float* Wp = (const float*)d_in[6];
    const float* bp = (const float*)d_in[7];
    const float* Wf = (const float*)d_in[8];
    const float* bf = (const float*)d_in[9];
    float* out = (float*)d_out;

    // ws map (bytes), peak ~98 MB:
    // [0,16M)   WpG
    // [32M,64M) Qraw bf16 -> Y (mgemm1 in place)
    // [64M,96M) Kraw bf16
    // [96M,..)  Wqbf, Wkbf, Wfbf, then zeroed stats region:
    //           ssqQ[T] ssqK[T] qwr[T] G[B*D] Sb[B]
    char* Wb = (char*)d_ws;
    u16* WpG = (u16*)Wb;
    u16* Qn  = (u16*)(Wb + 33554432ull);
    u16* Kn  = (u16*)(Wb + 67108864ull);
    char* S  = Wb + 100663296ull;
    u16* Wqbf = (u16*)S;
    u16* Wkbf = (u16*)(S + 524288ull);
    u16* Wfbf = (u16*)(S + 1048576ull);
    char* Z   = S + 1572864ull;
    float* SSQQ = (float*)Z;
    float* SSQK = (float*)(Z + 131072ull);
    float* QWR  = (float*)(Z + 262144ull);
    float* G    = (float*)(Z + 393216ull);
    float* Sb   = (float*)(Z + 458752ull);
    const size_t ZBYTES = 458752ull + 128ull;

    const dim3 blk(256);

    // 1. weights -> bf16
    convw_k<<<dim3(128, 3), blk, 0, stream>>>(Wq, Wk, Wf, Wqbf, Wkbf, Wfbf);
    // 2. zero the stats region (atomic accumulators)
    hipMemsetAsync(Z, 0, ZBYTES, stream);
    // 3. fused q/k projection (direct x read) + row-norm stats
    mgemm0<<<dim3(1024), dim3(512), 0, stream>>>(x, Wqbf, Wkbf, bq, bk, wg,
                                                 SSQQ, SSQK, QWR, Qn, Kn);
    // 4. finalize rscales, gctx coeff, Sb
    finalize_k<<<dim3(128), blk, 0, stream>>>(SSQQ, SSQK, QWR, Sb);
    // 5. graw = sum_n coeff_n * qraw_n
    gctx_k<<<dim3(8, B_), dim3(512), 0, stream>>>(QWR, Qn, G);
    // 6. WpG[b] = Wp * graw[b] * f_b
    scalewp_k<<<dim3(128, B_), blk, 0, stream>>>(Wp, G, Sb, WpG);
    // 7. Y = k_hat @ WpG[b]^T + bp + q_hat  (bf16, in place over Qn)
    mgemm12<1><<<dim3(1024), blk, 0, stream>>>(Kn, WpG, bp, SSQK, SSQQ, Qn,
                                               nullptr);
    // 8. out[b][e][n] = Wf x Y^T + bf  (fp32, final layout)
    mgemm12<2><<<dim3(1024), blk, 0, stream>>>(Wfbf, Qn, bf, nullptr, nullptr,
                                               nullptr, out);
}